// Round 1
// baseline (3285.611 us; speedup 1.0000x reference)
//
#include <hip/hip_runtime.h>
#include <hip/hip_bf16.h>
#include <stdint.h>

// Sizes (fixed by the problem)
#define VOCAB 50000
#define EMB   128
#define HID   256
#define G4    1024   // 4*HID, gate order i,f,g,o (PyTorch)
#define BATCH 256
#define SEQ   512

typedef __attribute__((ext_vector_type(8))) short bf16x8;  // 8 bf16 = 4 VGPRs
typedef __attribute__((ext_vector_type(4))) float f32x4;

__device__ __forceinline__ ushort f2bf(float f) {
  uint32_t u; __builtin_memcpy(&u, &f, 4);
  uint32_t r = (u + 0x7fffu + ((u >> 16) & 1u)) >> 16;  // RNE
  return (ushort)r;
}
__device__ __forceinline__ float bf2f(ushort u) {
  uint32_t x = ((uint32_t)u) << 16;
  float f; __builtin_memcpy(&f, &x, 4);
  return f;
}
__device__ __forceinline__ float sigm(float x) { return 1.f / (1.f + __expf(-x)); }
__device__ __forceinline__ float tanh_fast(float x) {
  float e2 = __expf(2.f * x);
  return (e2 - 1.f) / (e2 + 1.f);
}

// ---------------------------------------------------------------------------
// K1: proj_table[v][g] = sum_e emb[v][e]*W_ih[g][e] + b_ih[g] + b_hh[g]  (bf16)
// Per wave: 64 vocab rows x all 1024 cols, K=128. MFMA 16x16x32 bf16.
// A-frag: lane l holds A[m=l&15][k=(l>>4)*8 + i], B-frag: B[k][n=l&15] = W_ih[n][k].
// C: col=lane&15, row=(lane>>4)*4+reg.
// ---------------------------------------------------------------------------
__global__ __launch_bounds__(256) void k_proj(
    const float* __restrict__ emb, const float* __restrict__ W_ih,
    const float* __restrict__ b_ih, const float* __restrict__ b_hh,
    ushort* __restrict__ proj) {
  const int lane = threadIdx.x & 63;
  const int wv = threadIdx.x >> 6;                   // 0..3
  const int vbase = (blockIdx.x * 4 + wv) * 64;      // this wave's 64 rows
  const int lm = lane & 15, lq = lane >> 4;

  bf16x8 A[4][4];  // [m-tile][k-tile]
  #pragma unroll
  for (int mt = 0; mt < 4; ++mt) {
    int v = vbase + mt * 16 + lm;
    int vc = v < VOCAB ? v : 0;                      // clamp; stores guarded below
    const float* rp = emb + (size_t)vc * EMB;
    #pragma unroll
    for (int kt = 0; kt < 4; ++kt) {
      const float* p = rp + kt * 32 + lq * 8;
      #pragma unroll
      for (int i = 0; i < 8; ++i) A[mt][kt][i] = (short)f2bf(p[i]);
    }
  }
  for (int nt = 0; nt < 64; ++nt) {
    const int g = nt * 16 + lm;
    bf16x8 B[4];
    #pragma unroll
    for (int kt = 0; kt < 4; ++kt) {
      const float* p = W_ih + (size_t)g * EMB + kt * 32 + lq * 8;
      #pragma unroll
      for (int i = 0; i < 8; ++i) B[kt][i] = (short)f2bf(p[i]);
    }
    const float bias = b_ih[g] + b_hh[g];
    #pragma unroll
    for (int mt = 0; mt < 4; ++mt) {
      f32x4 acc = {0.f, 0.f, 0.f, 0.f};
      #pragma unroll
      for (int kt = 0; kt < 4; ++kt)
        acc = __builtin_amdgcn_mfma_f32_16x16x32_bf16(A[mt][kt], B[kt], acc, 0, 0, 0);
      #pragma unroll
      for (int r = 0; r < 4; ++r) {
        int row = vbase + mt * 16 + lq * 4 + r;
        if (row < VOCAB) proj[(size_t)row * G4 + g] = f2bf(acc[r] + bias);
      }
    }
  }
}

// ---------------------------------------------------------------------------
// K2: pre-swizzle W_hh (f32 [1024][256]) into bf16 MFMA B-fragment order:
// frag f = ((w*4+nt)*8+kt)*64 + lane; elem i: W_hh[g][k], g=nt*256+w*16+(l&15),
// k = kt*32 + (l>>4)*8 + i.  Main kernel then streams with coalesced dwordx4.
// ---------------------------------------------------------------------------
__global__ __launch_bounds__(256) void k_w2(const float* __restrict__ Whh,
                                            ushort* __restrict__ W2) {
  const int f = blockIdx.x * 256 + threadIdx.x;      // 0..32767
  const int l = f & 63, kt = (f >> 6) & 7, nt = (f >> 9) & 3, w = f >> 11;
  const int g = nt * 256 + w * 16 + (l & 15);
  const int k0 = kt * 32 + (l >> 4) * 8;
  const float* p = Whh + (size_t)g * HID + k0;
  bf16x8 o;
  #pragma unroll
  for (int i = 0; i < 8; ++i) o[i] = (short)f2bf(p[i]);
  *(bf16x8*)(W2 + (size_t)f * 8) = o;
}

// ---------------------------------------------------------------------------
// K3: persistent LSTM. 16 blocks x 1024 threads (16 waves). Block owns 16 batch
// rows; wave w owns hidden slice j in [w*16,w*16+16) across all 4 gates, so the
// c/h update is entirely wave-local. h ping-pongs in LDS (bf16, XOR-swizzled),
// c lives in registers. W_hh streamed from L2 as pre-swizzled fragments.
// ---------------------------------------------------------------------------
__global__ __launch_bounds__(1024, 4) void k_lstm(
    const int* __restrict__ x, const ushort* __restrict__ proj,
    const ushort* __restrict__ W2, const float* __restrict__ W_fc,
    const float* __restrict__ b_fc, float* __restrict__ out) {
  __shared__ __align__(16) ushort hbuf[2][16 * 256];  // [b][j] bf16, swizzled
  __shared__ float h32[16 * 257];                     // final h, f32, padded

  const int tid = threadIdx.x;
  const int lane = tid & 63, wv = tid >> 6;           // wave 0..15
  const int lm = lane & 15, lq = lane >> 4;
  const int b0 = blockIdx.x * 16;

  for (int i = tid; i < 16 * 256; i += 1024) hbuf[0][i] = 0;  // h0 = 0

  float c[4] = {0.f, 0.f, 0.f, 0.f};                  // c0 = 0 (4 b-rows/lane)

  int gcol[4];
  #pragma unroll
  for (int nt = 0; nt < 4; ++nt) gcol[nt] = nt * 256 + wv * 16 + lm;

  // xp prefetch regs for t=0: xpv[nt][r] = proj[x[b(r)][t]][gcol[nt]]
  ushort xpv[4][4];
  #pragma unroll
  for (int r = 0; r < 4; ++r) {
    const int bl = lq * 4 + r;
    const int idx = x[(b0 + bl) * SEQ + 0];
    const ushort* rp = proj + (size_t)idx * G4;
    #pragma unroll
    for (int nt = 0; nt < 4; ++nt) xpv[nt][r] = rp[gcol[nt]];
  }
  __syncthreads();

  const ushort* w2w = W2 + (size_t)wv * 4 * 8 * 64 * 8;  // wave's frag base

  int cur = 0;
  #pragma clang loop unroll(disable)
  for (int t = 0; t < SEQ; ++t) {
    // A-frags: h[b=lm][k-chunk] from swizzled LDS (2-way conflicts only)
    bf16x8 A[8];
    {
      const ushort* hb = hbuf[cur];
      #pragma unroll
      for (int kt = 0; kt < 8; ++kt) {
        int byte = (lm * 512 + kt * 64 + lq * 16) ^ ((lm & 7) << 4);
        A[kt] = *(const bf16x8*)((const char*)hb + byte);
      }
    }
    // acc init = x_proj (+ biases already folded into proj_table)
    f32x4 acc[4];
    #pragma unroll
    for (int nt = 0; nt < 4; ++nt) {
      #pragma unroll
      for (int r = 0; r < 4; ++r) acc[nt][r] = bf2f(xpv[nt][r]);
    }
    // prefetch next step's x_proj (hidden under the W2 stream below)
    if (t + 1 < SEQ) {
      #pragma unroll
      for (int r = 0; r < 4; ++r) {
        const int bl = lq * 4 + r;
        const int idx = x[(b0 + bl) * SEQ + t + 1];
        const ushort* rp = proj + (size_t)idx * G4;
        #pragma unroll
        for (int nt = 0; nt < 4; ++nt) xpv[nt][r] = rp[gcol[nt]];
      }
    }
    // W_hh stream + MFMA (the round-1 bottleneck: 512KB/step from L2).
    // Opaque asm keeps LICM from hoisting 128 regs of loop-invariant loads.
    {
      unsigned long long u = (unsigned long long)(uintptr_t)w2w;
      asm volatile("" : "+v"(u));
      const bf16x8* wb = (const bf16x8*)(uintptr_t)u;
      #pragma unroll
      for (int nt = 0; nt < 4; ++nt) {
        #pragma unroll
        for (int kt = 0; kt < 8; ++kt) {
          bf16x8 B = wb[(nt * 8 + kt) * 64 + lane];
          acc[nt] = __builtin_amdgcn_mfma_f32_16x16x32_bf16(A[kt], B, acc[nt], 0, 0, 0);
        }
      }
    }
    // activations + state update; lane owns (b = lq*4+r, j = wv*16+lm)
    const int nxt = cur ^ 1;
    #pragma unroll
    for (int r = 0; r < 4; ++r) {
      float si = sigm(acc[0][r]);
      float sf = sigm(acc[1][r]);
      float tg = tanh_fast(acc[2][r]);
      float so = sigm(acc[3][r]);
      float cn = sf * c[r] + si * tg;
      c[r] = cn;
      float h = so * tanh_fast(cn);
      const int bl = lq * 4 + r;
      const int j = wv * 16 + lm;
      int byte = (bl * 512 + j * 2) ^ ((bl & 7) << 4);
      *(ushort*)((char*)hbuf[nxt] + byte) = f2bf(h);
      if (t == SEQ - 1) h32[bl * 257 + j] = h;
    }
    cur = nxt;
    __syncthreads();
  }

  // FC + sigmoid epilogue: logits[b] = sum_j h[b][j]*W_fc[j] + b_fc
  if (tid < 256) {
    const int bl = tid >> 4, seg = tid & 15;
    float p = 0.f;
    #pragma unroll
    for (int jj = 0; jj < 16; ++jj) {
      const int j = seg * 16 + jj;
      p += h32[bl * 257 + j] * W_fc[j];
    }
    p += __shfl_xor(p, 1);
    p += __shfl_xor(p, 2);
    p += __shfl_xor(p, 4);
    p += __shfl_xor(p, 8);
    if (seg == 0) out[b0 + bl] = sigm(p + b_fc[0]);
  }
}

// ---------------------------------------------------------------------------
extern "C" void kernel_launch(void* const* d_in, const int* in_sizes, int n_in,
                              void* d_out, int out_size, void* d_ws, size_t ws_size,
                              hipStream_t stream) {
  const int*   x    = (const int*)d_in[0];
  const float* emb  = (const float*)d_in[1];
  const float* W_ih = (const float*)d_in[2];
  const float* W_hh = (const float*)d_in[3];
  const float* b_ih = (const float*)d_in[4];
  const float* b_hh = (const float*)d_in[5];
  const float* W_fc = (const float*)d_in[6];
  const float* b_fc = (const float*)d_in[7];
  float* out = (float*)d_out;

  // Workspace layout: proj_table bf16 [50000][1024] = 102,400,000 B,
  // then W2 (swizzled bf16 W_hh) 524,288 B. Total ~98.2 MiB (assumed <= ws_size).
  ushort* proj = (ushort*)d_ws;
  ushort* W2   = (ushort*)((char*)d_ws + 102400000);

  k_proj<<<dim3(196), dim3(256), 0, stream>>>(emb, W_ih, b_ih, b_hh, proj);
  k_w2<<<dim3(128), dim3(256), 0, stream>>>(W_hh, W2);
  k_lstm<<<dim3(16), dim3(1024), 0, stream>>>(x, proj, W2, W_fc, b_fc, out);
}

// Round 2
// 2857.953 us; speedup vs baseline: 1.1496x; 1.1496x over previous
//
#include <hip/hip_runtime.h>
#include <hip/hip_bf16.h>
#include <stdint.h>

#define VOCAB 50000
#define EMB   128
#define HID   256
#define G4    1024   // 4*HID, gate order i,f,g,o
#define BATCH 256
#define SEQ   512

typedef __attribute__((ext_vector_type(8))) short bf16x8;
typedef __attribute__((ext_vector_type(4))) float f32x4;

__device__ __forceinline__ ushort f2bf(float f) {
  uint32_t u; __builtin_memcpy(&u, &f, 4);
  uint32_t r = (u + 0x7fffu + ((u >> 16) & 1u)) >> 16;  // RNE
  return (ushort)r;
}
__device__ __forceinline__ float bf2f(ushort u) {
  uint32_t x = ((uint32_t)u) << 16;
  float f; __builtin_memcpy(&f, &x, 4);
  return f;
}
__device__ __forceinline__ float sigm(float x) { return 1.f / (1.f + __expf(-x)); }
__device__ __forceinline__ float tanh_fast(float x) {
  float e2 = __expf(2.f * x);
  return (e2 - 1.f) / (e2 + 1.f);
}

// ---------------------------------------------------------------------------
// K0: zero the pair-sync flags (graph-replay safe: flags are monotonic per
// launch, so they must start at 0 every launch).
// ---------------------------------------------------------------------------
__global__ __launch_bounds__(512) void k_reset(unsigned* __restrict__ flags) {
  flags[threadIdx.x] = 0;  // 512 uints = 32 blocks x 16-uint (64B) slots
}

// ---------------------------------------------------------------------------
// K1: proj_table[v][g] = emb[v]@W_ih[g] + b_ih[g] + b_hh[g]  (bf16) — unchanged.
// ---------------------------------------------------------------------------
__global__ __launch_bounds__(256) void k_proj(
    const float* __restrict__ emb, const float* __restrict__ W_ih,
    const float* __restrict__ b_ih, const float* __restrict__ b_hh,
    ushort* __restrict__ proj) {
  const int lane = threadIdx.x & 63;
  const int wv = threadIdx.x >> 6;
  const int vbase = (blockIdx.x * 4 + wv) * 64;
  const int lm = lane & 15, lq = lane >> 4;

  bf16x8 A[4][4];
  #pragma unroll
  for (int mt = 0; mt < 4; ++mt) {
    int v = vbase + mt * 16 + lm;
    int vc = v < VOCAB ? v : 0;
    const float* rp = emb + (size_t)vc * EMB;
    #pragma unroll
    for (int kt = 0; kt < 4; ++kt) {
      const float* p = rp + kt * 32 + lq * 8;
      #pragma unroll
      for (int i = 0; i < 8; ++i) A[mt][kt][i] = (short)f2bf(p[i]);
    }
  }
  for (int nt = 0; nt < 64; ++nt) {
    const int g = nt * 16 + lm;
    bf16x8 B[4];
    #pragma unroll
    for (int kt = 0; kt < 4; ++kt) {
      const float* p = W_ih + (size_t)g * EMB + kt * 32 + lq * 8;
      #pragma unroll
      for (int i = 0; i < 8; ++i) B[kt][i] = (short)f2bf(p[i]);
    }
    const float bias = b_ih[g] + b_hh[g];
    #pragma unroll
    for (int mt = 0; mt < 4; ++mt) {
      f32x4 acc = {0.f, 0.f, 0.f, 0.f};
      #pragma unroll
      for (int kt = 0; kt < 4; ++kt)
        acc = __builtin_amdgcn_mfma_f32_16x16x32_bf16(A[mt][kt], B[kt], acc, 0, 0, 0);
      #pragma unroll
      for (int r = 0; r < 4; ++r) {
        int row = vbase + mt * 16 + lq * 4 + r;
        if (row < VOCAB) proj[(size_t)row * G4 + g] = f2bf(acc[r] + bias);
      }
    }
  }
}

// ---------------------------------------------------------------------------
// K2: pre-swizzle W_hh into per-(parity,wave) MFMA B-fragment order with the
// K-chunks permuted so slots 0..3 are the block's LOCAL j-range K-chunks and
// 4..7 the REMOTE ones (compile-time indexing in the main loop, rule #20).
// frag f = (((p*8+wv)*4+nt)*8+kc)*64 + lane.
// ---------------------------------------------------------------------------
__global__ __launch_bounds__(256) void k_w2(const float* __restrict__ Whh,
                                            ushort* __restrict__ W2) {
  const int f = blockIdx.x * 256 + threadIdx.x;      // 0..32767
  const int l = f & 63, kc = (f >> 6) & 7, nt = (f >> 9) & 3;
  const int wv = (f >> 11) & 7, p = (f >> 14) & 1;
  const int ktg = (kc < 4) ? (4 * p + kc) : (4 * (1 - p) + (kc - 4));
  const int g = nt * 256 + p * 128 + wv * 16 + (l & 15);
  const int k0 = ktg * 32 + (l >> 4) * 8;
  const float* src = Whh + (size_t)g * HID + k0;
  bf16x8 o;
  #pragma unroll
  for (int i = 0; i < 8; ++i) o[i] = (short)f2bf(src[i]);
  *(bf16x8*)(W2 + (size_t)f * 8) = o;
}

// ---------------------------------------------------------------------------
// K3: persistent pair-split LSTM. 32 blocks x 512 threads (8 waves).
// Block (p,g): batch rows [16g,16g+16), hidden cols j in [128p,128p+128).
// W_hh slice fully VGPR-resident (128 regs/lane). Per step the block computes
// its h-half, writes 4KB to L2, release-flags; partner acquire-spins, reads.
// Local-half MFMAs + x_proj prefetch hide the partner RTT.
// ---------------------------------------------------------------------------
__global__ __launch_bounds__(512, 2) void k_lstm(
    const int* __restrict__ x, const ushort* __restrict__ proj,
    const ushort* __restrict__ W2, const float* __restrict__ W_fc,
    const float* __restrict__ b_fc, float* __restrict__ out,
    ushort* __restrict__ hx, float* __restrict__ fcpart,
    unsigned* __restrict__ flags) {
  __shared__ __align__(16) ushort hbuf[2][16 * 128];  // local j-half, swizzled
  __shared__ float red[8][16];

  const int tid = threadIdx.x;
  const int lane = tid & 63, wv = tid >> 6;           // 8 waves
  const int lm = lane & 15, lq = lane >> 4;
  const int g16 = blockIdx.x & 15;                    // batch group
  const int p = blockIdx.x >> 4;                      // j-parity (0/1)
  const int b0 = g16 * 16;

  // --- weight residency: 32 fragments = 128 VGPRs/lane ---
  bf16x8 Wf[4][8];
  {
    const bf16x8* wb = (const bf16x8*)W2;
    const int base = (p * 8 + wv) * 32;               // frag index base
    #pragma unroll
    for (int nt = 0; nt < 4; ++nt)
      #pragma unroll
      for (int kc = 0; kc < 8; ++kc)
        Wf[nt][kc] = wb[(size_t)(base + nt * 8 + kc) * 64 + lane];
  }

  for (int i = tid; i < 16 * 128; i += 512) hbuf[0][i] = 0;  // h(0) = 0

  float c[4] = {0.f, 0.f, 0.f, 0.f};
  float hlast[4] = {0.f, 0.f, 0.f, 0.f};

  int gcol[4];
  #pragma unroll
  for (int nt = 0; nt < 4; ++nt) gcol[nt] = nt * 256 + p * 128 + wv * 16 + lm;

  // x_proj prefetch for t=0
  ushort xpv[4][4];
  #pragma unroll
  for (int r = 0; r < 4; ++r) {
    const int idx = x[(b0 + lq * 4 + r) * SEQ + 0];
    const ushort* rp = proj + (size_t)idx * G4;
    #pragma unroll
    for (int nt = 0; nt < 4; ++nt) xpv[nt][r] = rp[gcol[nt]];
  }

  ushort* my_h = hx + (size_t)((p * 16 + g16) * 2) * 2048;         // 2 slots x 4KB
  const ushort* rm_h = hx + (size_t)(((1 - p) * 16 + g16) * 2) * 2048;
  unsigned* my_flag = flags + blockIdx.x * 16;
  const unsigned* rm_flag = flags + ((1 - p) * 16 + g16) * 16;

  __syncthreads();

  int cur = 0;
  #pragma clang loop unroll(disable)
  for (int t = 0; t < SEQ; ++t) {
    // 1) prefetch next step's x_proj (overlaps MFMA + partner RTT)
    ushort xpn[4][4];
    {
      const int tt = (t + 1 < SEQ) ? t + 1 : SEQ - 1;
      #pragma unroll
      for (int r = 0; r < 4; ++r) {
        const int idx = x[(b0 + lq * 4 + r) * SEQ + tt];
        const ushort* rp = proj + (size_t)idx * G4;
        #pragma unroll
        for (int nt = 0; nt < 4; ++nt) xpn[nt][r] = rp[gcol[nt]];
      }
    }
    __builtin_amdgcn_sched_barrier(0);  // keep prefetch issued before the spin

    f32x4 acc[4];
    #pragma unroll
    for (int nt = 0; nt < 4; ++nt) {
      #pragma unroll
      for (int r = 0; r < 4; ++r) acc[nt][r] = bf2f(xpv[nt][r]);
    }

    if (t > 0) {
      // local-half A-frags from LDS (swizzled) + local MFMAs
      bf16x8 Al[4];
      {
        const char* hb = (const char*)hbuf[cur];
        #pragma unroll
        for (int c4 = 0; c4 < 4; ++c4) {
          int byte = (lm * 256 + c4 * 64 + lq * 16) ^ ((lm & 7) << 4);
          Al[c4] = *(const bf16x8*)(hb + byte);
        }
      }
      #pragma unroll
      for (int nt = 0; nt < 4; ++nt)
        #pragma unroll
        for (int c4 = 0; c4 < 4; ++c4)
          acc[nt] = __builtin_amdgcn_mfma_f32_16x16x32_bf16(Al[c4], Wf[nt][c4], acc[nt], 0, 0, 0);

      // wait for partner's h(t) half (release/acquire handshake, agent scope)
      while (__hip_atomic_load(rm_flag, __ATOMIC_ACQUIRE, __HIP_MEMORY_SCOPE_AGENT) <
             (unsigned)t)
        __builtin_amdgcn_s_sleep(1);

      const char* rb = (const char*)(rm_h + cur * 2048);
      bf16x8 Ar[4];
      #pragma unroll
      for (int c4 = 0; c4 < 4; ++c4)
        Ar[c4] = *(const bf16x8*)(rb + lm * 256 + c4 * 64 + lq * 16);
      #pragma unroll
      for (int nt = 0; nt < 4; ++nt)
        #pragma unroll
        for (int c4 = 0; c4 < 4; ++c4)
          acc[nt] = __builtin_amdgcn_mfma_f32_16x16x32_bf16(Ar[c4], Wf[nt][4 + c4], acc[nt], 0, 0, 0);
    }

    // activations: lane owns (b = lq*4+r, j = p*128 + wv*16 + lm)
    const int nxt = cur ^ 1;
    ushort hh[4];
    #pragma unroll
    for (int r = 0; r < 4; ++r) {
      float si = sigm(acc[0][r]);
      float sf = sigm(acc[1][r]);
      float tg = tanh_fast(acc[2][r]);
      float so = sigm(acc[3][r]);
      float cn = sf * c[r] + si * tg;
      c[r] = cn;
      float h = so * tanh_fast(cn);
      hlast[r] = h;
      hh[r] = f2bf(h);
      const int bl = lq * 4 + r;
      int byte = (bl * 256 + (wv * 16 + lm) * 2) ^ ((bl & 7) << 4);
      *(ushort*)((char*)hbuf[nxt] + byte) = hh[r];
    }
    if (t + 1 < SEQ) {
      ushort* mb = my_h + nxt * 2048;
      #pragma unroll
      for (int r = 0; r < 4; ++r) {
        const int bl = lq * 4 + r;
        mb[bl * 128 + wv * 16 + lm] = hh[r];
      }
      asm volatile("s_waitcnt vmcnt(0)" ::: "memory");  // drain h stores
    }
    __syncthreads();
    if (t + 1 < SEQ && tid == 0)
      __hip_atomic_store(my_flag, (unsigned)(t + 1), __ATOMIC_RELEASE,
                         __HIP_MEMORY_SCOPE_AGENT);
    #pragma unroll
    for (int nt = 0; nt < 4; ++nt)
      #pragma unroll
      for (int r = 0; r < 4; ++r) xpv[nt][r] = xpn[nt][r];
    cur = nxt;
  }

  // --- FC + sigmoid epilogue (pair-split partial dot products) ---
  float pl[4];
  const float wfc = W_fc[p * 128 + wv * 16 + lm];
  #pragma unroll
  for (int r = 0; r < 4; ++r) pl[r] = hlast[r] * wfc;
  #pragma unroll
  for (int d = 1; d < 16; d <<= 1) {
    #pragma unroll
    for (int r = 0; r < 4; ++r) pl[r] += __shfl_xor(pl[r], d);
  }
  if (lm == 0) {
    #pragma unroll
    for (int r = 0; r < 4; ++r) red[wv][lq * 4 + r] = pl[r];
  }
  __syncthreads();
  if (tid < 16) {
    float s = 0.f;
    #pragma unroll
    for (int w = 0; w < 8; ++w) s += red[w][tid];
    if (p == 1) {
      fcpart[g16 * 16 + tid] = s;
      asm volatile("s_waitcnt vmcnt(0)" ::: "memory");
      __hip_atomic_store(my_flag, (unsigned)(SEQ + 1), __ATOMIC_RELEASE,
                         __HIP_MEMORY_SCOPE_AGENT);
    } else {
      while (__hip_atomic_load(rm_flag, __ATOMIC_ACQUIRE, __HIP_MEMORY_SCOPE_AGENT) <
             (unsigned)(SEQ + 1))
        __builtin_amdgcn_s_sleep(1);
      float v = fcpart[g16 * 16 + tid];
      out[b0 + tid] = sigm(s + v + b_fc[0]);
    }
  }
}

// ---------------------------------------------------------------------------
extern "C" void kernel_launch(void* const* d_in, const int* in_sizes, int n_in,
                              void* d_out, int out_size, void* d_ws, size_t ws_size,
                              hipStream_t stream) {
  const int*   x    = (const int*)d_in[0];
  const float* emb  = (const float*)d_in[1];
  const float* W_ih = (const float*)d_in[2];
  const float* W_hh = (const float*)d_in[3];
  const float* b_ih = (const float*)d_in[4];
  const float* b_hh = (const float*)d_in[5];
  const float* W_fc = (const float*)d_in[6];
  const float* b_fc = (const float*)d_in[7];
  float* out = (float*)d_out;

  // ws layout: proj 102,400,000 B | W2 524,288 B | hx 262,144 B |
  //            fcpart 1,024 B | flags 2,048 B   (total ~98.4 MiB)
  char* ws = (char*)d_ws;
  ushort*   proj   = (ushort*)ws;
  ushort*   W2     = (ushort*)(ws + 102400000);
  ushort*   hx     = (ushort*)(ws + 102924288);
  float*    fcpart = (float*)(ws + 103186432);
  unsigned* flags  = (unsigned*)(ws + 103187456);

  k_reset<<<dim3(1), dim3(512), 0, stream>>>(flags);
  k_proj<<<dim3(196), dim3(256), 0, stream>>>(emb, W_ih, b_ih, b_hh, proj);
  k_w2<<<dim3(128), dim3(256), 0, stream>>>(W_hh, W2);
  k_lstm<<<dim3(32), dim3(512), 0, stream>>>(x, proj, W2, W_fc, b_fc, out,
                                             hx, fcpart, flags);
}

// Round 3
// 1791.461 us; speedup vs baseline: 1.8340x; 1.5953x over previous
//
#include <hip/hip_runtime.h>
#include <hip/hip_bf16.h>
#include <stdint.h>

#define VOCAB 50000
#define EMB   128
#define HID   256
#define G4    1024   // 4*HID, gate order i,f,g,o
#define BATCH 256
#define SEQ   512

typedef __attribute__((ext_vector_type(8))) short bf16x8;
typedef __attribute__((ext_vector_type(4))) float f32x4;
typedef __attribute__((ext_vector_type(4))) int   i32x4;

__device__ __forceinline__ ushort f2bf(float f) {
  uint32_t u; __builtin_memcpy(&u, &f, 4);
  uint32_t r = (u + 0x7fffu + ((u >> 16) & 1u)) >> 16;  // RNE
  return (ushort)r;
}
__device__ __forceinline__ float bf2f(ushort u) {
  uint32_t x = ((uint32_t)u) << 16;
  float f; __builtin_memcpy(&f, &x, 4);
  return f;
}
__device__ __forceinline__ float sigm(float x) { return 1.f / (1.f + __expf(-x)); }
__device__ __forceinline__ float tanh_fast(float x) {
  float e2 = __expf(2.f * x);
  return (e2 - 1.f) / (e2 + 1.f);
}

// --- cache-bypass (sc0 sc1) ops: served at the coherent point (L3/MALL),
// no whole-L2 invalidate/writeback like compiler agent-scope atomics ---
__device__ __forceinline__ void ld128_sys(bf16x8& d, const void* p) {
  asm volatile("global_load_dwordx4 %0, %1, off sc0 sc1"
               : "=&v"(d) : "v"(p) : "memory");
}
__device__ __forceinline__ unsigned ld_flag_sys(const unsigned* p) {
  unsigned v;
  asm volatile("global_load_dword %0, %1, off sc0 sc1\n\t"
               "s_waitcnt vmcnt(0)"
               : "=&v"(v) : "v"(p) : "memory");
  return v;
}
__device__ __forceinline__ void st16_sys(void* p, unsigned v) {
  asm volatile("global_store_short %0, %1, off sc0 sc1"
               :: "v"(p), "v"(v) : "memory");
}
__device__ __forceinline__ void st32_sys(void* p, unsigned v) {
  asm volatile("global_store_dword %0, %1, off sc0 sc1"
               :: "v"(p), "v"(v) : "memory");
}

// ---------------------------------------------------------------------------
// K0: zero pair-sync flags each launch (graph-replay safe).
// ---------------------------------------------------------------------------
__global__ __launch_bounds__(512) void k_reset(unsigned* __restrict__ flags) {
  flags[threadIdx.x] = 0;
}

// ---------------------------------------------------------------------------
// K1: proj_table[v][g] = emb[v]@W_ih[g] + b_ih[g] + b_hh[g]  (bf16).
// ---------------------------------------------------------------------------
__global__ __launch_bounds__(256) void k_proj(
    const float* __restrict__ emb, const float* __restrict__ W_ih,
    const float* __restrict__ b_ih, const float* __restrict__ b_hh,
    ushort* __restrict__ proj) {
  const int lane = threadIdx.x & 63;
  const int wv = threadIdx.x >> 6;
  const int vbase = (blockIdx.x * 4 + wv) * 64;
  const int lm = lane & 15, lq = lane >> 4;

  bf16x8 A[4][4];
  #pragma unroll
  for (int mt = 0; mt < 4; ++mt) {
    int v = vbase + mt * 16 + lm;
    int vc = v < VOCAB ? v : 0;
    const float* rp = emb + (size_t)vc * EMB;
    #pragma unroll
    for (int kt = 0; kt < 4; ++kt) {
      const float* p = rp + kt * 32 + lq * 8;
      #pragma unroll
      for (int i = 0; i < 8; ++i) A[mt][kt][i] = (short)f2bf(p[i]);
    }
  }
  for (int nt = 0; nt < 64; ++nt) {
    const int g = nt * 16 + lm;
    bf16x8 B[4];
    #pragma unroll
    for (int kt = 0; kt < 4; ++kt) {
      const float* p = W_ih + (size_t)g * EMB + kt * 32 + lq * 8;
      #pragma unroll
      for (int i = 0; i < 8; ++i) B[kt][i] = (short)f2bf(p[i]);
    }
    const float bias = b_ih[g] + b_hh[g];
    #pragma unroll
    for (int mt = 0; mt < 4; ++mt) {
      f32x4 acc = {0.f, 0.f, 0.f, 0.f};
      #pragma unroll
      for (int kt = 0; kt < 4; ++kt)
        acc = __builtin_amdgcn_mfma_f32_16x16x32_bf16(A[mt][kt], B[kt], acc, 0, 0, 0);
      #pragma unroll
      for (int r = 0; r < 4; ++r) {
        int row = vbase + mt * 16 + lq * 4 + r;
        if (row < VOCAB) proj[(size_t)row * G4 + g] = f2bf(acc[r] + bias);
      }
    }
  }
}

// ---------------------------------------------------------------------------
// K2: pre-swizzle W_hh into per-(parity,wave) MFMA B-fragment order; K-chunk
// slots 0..3 = block-local j-range, 4..7 = remote (static loop indices).
// ---------------------------------------------------------------------------
__global__ __launch_bounds__(256) void k_w2(const float* __restrict__ Whh,
                                            ushort* __restrict__ W2) {
  const int f = blockIdx.x * 256 + threadIdx.x;      // 0..32767
  const int l = f & 63, kc = (f >> 6) & 7, nt = (f >> 9) & 3;
  const int wv = (f >> 11) & 7, p = (f >> 14) & 1;
  const int ktg = (kc < 4) ? (4 * p + kc) : (4 * (1 - p) + (kc - 4));
  const int g = nt * 256 + p * 128 + wv * 16 + (l & 15);
  const int k0 = ktg * 32 + (l >> 4) * 8;
  const float* src = Whh + (size_t)g * HID + k0;
  bf16x8 o;
  #pragma unroll
  for (int i = 0; i < 8; ++i) o[i] = (short)f2bf(src[i]);
  *(bf16x8*)(W2 + (size_t)f * 8) = o;
}

// ---------------------------------------------------------------------------
// K3: persistent pair-split LSTM, weights PINNED in VGPRs (opaque-asm so the
// compiler cannot sink the loads back into the loop — round-2 failure mode).
// ---------------------------------------------------------------------------
__global__ __launch_bounds__(512, 2) void k_lstm(
    const int* __restrict__ x, const ushort* __restrict__ proj,
    const ushort* __restrict__ W2, const float* __restrict__ W_fc,
    const float* __restrict__ b_fc, float* __restrict__ out,
    ushort* __restrict__ hx, float* __restrict__ fcpart,
    unsigned* __restrict__ flags) {
  __shared__ __align__(16) ushort hbuf[2][16 * 128];  // local j-half, swizzled
  __shared__ __align__(16) int xlds[SEQ * 16];        // x transposed [t][bl]
  __shared__ float red[8][16];

  const int tid = threadIdx.x;
  const int lane = tid & 63, wv = tid >> 6;           // 8 waves
  const int lm = lane & 15, lq = lane >> 4;
  const int g16 = blockIdx.x & 15;                    // batch group
  const int p = blockIdx.x >> 4;                      // j-parity
  const int b0 = g16 * 16;

  // --- weight residency: 32 fragments = 128 VGPRs/lane, PINNED ---
  bf16x8 Wf[4][8];
  {
    const bf16x8* wb = (const bf16x8*)W2;
    const int base = (p * 8 + wv) * 32;
    #pragma unroll
    for (int nt = 0; nt < 4; ++nt)
      #pragma unroll
      for (int kc = 0; kc < 8; ++kc)
        Wf[nt][kc] = wb[(size_t)(base + nt * 8 + kc) * 64 + lane];
    #pragma unroll
    for (int nt = 0; nt < 4; ++nt)
      #pragma unroll
      for (int kc = 0; kc < 8; ++kc)
        asm volatile("" : "+v"(Wf[nt][kc]));          // opaque: loads can't sink
  }

  // x preload transposed: xlds[t*16+bl] (coalesced global reads)
  for (int i = tid; i < SEQ * 16; i += 512) {
    int bl = i >> 9, t = i & 511;
    xlds[t * 16 + bl] = x[(b0 + bl) * SEQ + t];
  }
  for (int i = tid; i < 16 * 128; i += 512) hbuf[0][i] = 0;

  unsigned* my_flag = flags + blockIdx.x * 16;
  const unsigned* rm_flag = flags + ((1 - p) * 16 + g16) * 16;
  ushort* my_h = hx + (size_t)((p * 16 + g16) * 2) * 2048;
  const ushort* rm_h = hx + (size_t)(((1 - p) * 16 + g16) * 2) * 2048;

  float c[4] = {0.f, 0.f, 0.f, 0.f};
  float hlast[4] = {0.f, 0.f, 0.f, 0.f};

  int gcol[4];
  #pragma unroll
  for (int nt = 0; nt < 4; ++nt) gcol[nt] = nt * 256 + p * 128 + wv * 16 + lm;

  __syncthreads();

  // t=0 x_proj gather
  ushort xpv[4][4];
  {
    i32x4 i0 = *(const i32x4*)&xlds[lq * 4];
    #pragma unroll
    for (int r = 0; r < 4; ++r) {
      const ushort* rp = proj + (size_t)i0[r] * G4;
      #pragma unroll
      for (int nt = 0; nt < 4; ++nt) xpv[nt][r] = rp[gcol[nt]];
    }
  }

  int cur = 0;
  #pragma clang loop unroll(disable)
  for (int t = 0; t < SEQ; ++t) {
    const int nxt = cur ^ 1;
    const int tt = (t + 1 < SEQ) ? t + 1 : SEQ - 1;
    i32x4 idx4 = *(const i32x4*)&xlds[tt * 16 + lq * 4];

    f32x4 acc[4];
    #pragma unroll
    for (int nt = 0; nt < 4; ++nt)
      #pragma unroll
      for (int r = 0; r < 4; ++r) acc[nt][r] = bf2f(xpv[nt][r]);

    if (t > 0) {
      // local A-frags from swizzled LDS
      bf16x8 Al[4];
      {
        const char* hb = (const char*)hbuf[cur];
        #pragma unroll
        for (int c4 = 0; c4 < 4; ++c4) {
          int byte = (lm * 256 + c4 * 64 + lq * 16) ^ ((lm & 7) << 4);
          Al[c4] = *(const bf16x8*)(hb + byte);
        }
      }
      // poll partner flag (steady state: already set)
      while (ld_flag_sys(rm_flag) < (unsigned)t) {}
      // issue 4 remote h loads FIRST (oldest in vmcnt queue) ...
      bf16x8 Ar[4];
      {
        const char* rb = (const char*)(rm_h + cur * 2048);
        ld128_sys(Ar[0], rb + (lm * 256 + 0 * 64 + lq * 16));
        ld128_sys(Ar[1], rb + (lm * 256 + 1 * 64 + lq * 16));
        ld128_sys(Ar[2], rb + (lm * 256 + 2 * 64 + lq * 16));
        ld128_sys(Ar[3], rb + (lm * 256 + 3 * 64 + lq * 16));
      }
      // ... then 16 next-step gather loads (stay in flight past vmcnt(16))
      #pragma unroll
      for (int r = 0; r < 4; ++r) {
        const ushort* rp = proj + (size_t)idx4[r] * G4;
        #pragma unroll
        for (int nt = 0; nt < 4; ++nt) xpv[nt][r] = rp[gcol[nt]];
      }
      // local MFMAs hide the remote RTT
      #pragma unroll
      for (int c4 = 0; c4 < 4; ++c4)
        #pragma unroll
        for (int nt = 0; nt < 4; ++nt)
          acc[nt] = __builtin_amdgcn_mfma_f32_16x16x32_bf16(Al[c4], Wf[nt][c4], acc[nt], 0, 0, 0);
      // wait ONLY the 4 oldest (remote) loads; gathers keep flying
      asm volatile("s_waitcnt vmcnt(16)" ::: "memory");
      __builtin_amdgcn_sched_barrier(0);
      #pragma unroll
      for (int c4 = 0; c4 < 4; ++c4)
        #pragma unroll
        for (int nt = 0; nt < 4; ++nt)
          acc[nt] = __builtin_amdgcn_mfma_f32_16x16x32_bf16(Ar[c4], Wf[nt][4 + c4], acc[nt], 0, 0, 0);
    } else {
      // t==0: just issue the t=1 gathers
      #pragma unroll
      for (int r = 0; r < 4; ++r) {
        const ushort* rp = proj + (size_t)idx4[r] * G4;
        #pragma unroll
        for (int nt = 0; nt < 4; ++nt) xpv[nt][r] = rp[gcol[nt]];
      }
    }

    // activations: lane owns (b = lq*4+r, j = p*128 + wv*16 + lm)
    ushort hh[4];
    #pragma unroll
    for (int r = 0; r < 4; ++r) {
      float si = sigm(acc[0][r]);
      float sf = sigm(acc[1][r]);
      float tg = tanh_fast(acc[2][r]);
      float so = sigm(acc[3][r]);
      float cn = sf * c[r] + si * tg;
      c[r] = cn;
      float h = so * tanh_fast(cn);
      hlast[r] = h;
      hh[r] = f2bf(h);
      const int bl = lq * 4 + r;
      int byte = (bl * 256 + (wv * 16 + lm) * 2) ^ ((bl & 7) << 4);
      *(ushort*)((char*)hbuf[nxt] + byte) = hh[r];
    }
    if (t + 1 < SEQ) {
      ushort* mb = my_h + nxt * 2048;
      #pragma unroll
      for (int r = 0; r < 4; ++r)
        st16_sys(mb + (lq * 4 + r) * 128 + wv * 16 + lm, (unsigned)hh[r]);
    }
    // per-thread drain BEFORE barrier so tid0's flag can't pass other waves'
    // publish stores (syncthreads alone may only drain lgkmcnt).
    asm volatile("s_waitcnt vmcnt(0)" ::: "memory");
    __syncthreads();
    if (t + 1 < SEQ && tid == 0) st32_sys(my_flag, (unsigned)(t + 1));
    cur = nxt;
  }

  // --- FC + sigmoid epilogue (pair-split partials) ---
  float pl[4];
  const float wfc = W_fc[p * 128 + wv * 16 + lm];
  #pragma unroll
  for (int r = 0; r < 4; ++r) pl[r] = hlast[r] * wfc;
  #pragma unroll
  for (int d = 1; d < 16; d <<= 1) {
    #pragma unroll
    for (int r = 0; r < 4; ++r) pl[r] += __shfl_xor(pl[r], d);
  }
  if (lm == 0) {
    #pragma unroll
    for (int r = 0; r < 4; ++r) red[wv][lq * 4 + r] = pl[r];
  }
  __syncthreads();
  if (tid < 16) {
    float s = 0.f;
    #pragma unroll
    for (int w = 0; w < 8; ++w) s += red[w][tid];
    if (p == 1) {
      fcpart[g16 * 16 + tid] = s;
      asm volatile("s_waitcnt vmcnt(0)" ::: "memory");
      __hip_atomic_store(my_flag, (unsigned)(SEQ + 1), __ATOMIC_RELEASE,
                         __HIP_MEMORY_SCOPE_AGENT);
    } else {
      while (__hip_atomic_load(rm_flag, __ATOMIC_ACQUIRE, __HIP_MEMORY_SCOPE_AGENT) <
             (unsigned)(SEQ + 1))
        __builtin_amdgcn_s_sleep(1);
      float v = fcpart[g16 * 16 + tid];
      out[b0 + tid] = sigm(s + v + b_fc[0]);
    }
  }
}

// ---------------------------------------------------------------------------
extern "C" void kernel_launch(void* const* d_in, const int* in_sizes, int n_in,
                              void* d_out, int out_size, void* d_ws, size_t ws_size,
                              hipStream_t stream) {
  const int*   x    = (const int*)d_in[0];
  const float* emb  = (const float*)d_in[1];
  const float* W_ih = (const float*)d_in[2];
  const float* W_hh = (const float*)d_in[3];
  const float* b_ih = (const float*)d_in[4];
  const float* b_hh = (const float*)d_in[5];
  const float* W_fc = (const float*)d_in[6];
  const float* b_fc = (const float*)d_in[7];
  float* out = (float*)d_out;

  // ws: proj 102,400,000 | W2 524,288 | hx 262,144 | fcpart 1,024 | flags 2,048
  char* ws = (char*)d_ws;
  ushort*   proj   = (ushort*)ws;
  ushort*   W2     = (ushort*)(ws + 102400000);
  ushort*   hx     = (ushort*)(ws + 102924288);
  float*    fcpart = (float*)(ws + 103186432);
  unsigned* flags  = (unsigned*)(ws + 103187456);

  k_reset<<<dim3(1), dim3(512), 0, stream>>>(flags);
  k_proj<<<dim3(196), dim3(256), 0, stream>>>(emb, W_ih, b_ih, b_hh, proj);
  k_w2<<<dim3(128), dim3(256), 0, stream>>>(W_hh, W2);
  k_lstm<<<dim3(32), dim3(512), 0, stream>>>(x, proj, W2, W_fc, b_fc, out,
                                             hx, fcpart, flags);
}

// Round 5
// 1541.680 us; speedup vs baseline: 2.1312x; 1.1620x over previous
//
#include <hip/hip_runtime.h>
#include <hip/hip_bf16.h>
#include <stdint.h>

#define VOCAB 50000
#define EMB   128
#define HID   256
#define G4    1024   // 4*HID, gate order i,f,g,o
#define BATCH 256
#define SEQ   512

typedef __attribute__((ext_vector_type(8))) short bf16x8;
typedef __attribute__((ext_vector_type(4))) float f32x4;
typedef __attribute__((ext_vector_type(4))) int   i32x4;

__device__ __forceinline__ ushort f2bf(float f) {
  uint32_t u; __builtin_memcpy(&u, &f, 4);
  uint32_t r = (u + 0x7fffu + ((u >> 16) & 1u)) >> 16;  // RNE
  return (ushort)r;
}
__device__ __forceinline__ float bf2f(ushort u) {
  uint32_t x = ((uint32_t)u) << 16;
  float f; __builtin_memcpy(&f, &x, 4);
  return f;
}
__device__ __forceinline__ float sigm(float x) {
  return __builtin_amdgcn_rcpf(1.f + __expf(-x));
}
__device__ __forceinline__ float tanh_fast(float x) {
  float e2 = __expf(2.f * x);
  return (e2 - 1.f) * __builtin_amdgcn_rcpf(e2 + 1.f);
}

// --- system-coherent ops (sc0 sc1 -> MALL), round-3-proven ----------------
__device__ __forceinline__ void ldx4_sys(bf16x8& d, const void* p) {
  asm volatile("global_load_dwordx4 %0, %1, off sc0 sc1"
               : "=&v"(d) : "v"(p) : "memory");
}
__device__ __forceinline__ unsigned ld_flag_sys(const unsigned* p) {
  unsigned v;
  asm volatile("global_load_dword %0, %1, off sc0 sc1\n\t"
               "s_waitcnt vmcnt(0)"
               : "=&v"(v) : "v"(p) : "memory");
  return v;
}
// issue-only flag load: value is valid ONLY after a later s_waitcnt vmcnt(0)
__device__ __forceinline__ unsigned ld_flag_issue(const unsigned* p) {
  unsigned v;
  asm volatile("global_load_dword %0, %1, off sc0 sc1"
               : "=&v"(v) : "v"(p) : "memory");
  return v;
}
__device__ __forceinline__ void st16_sys(void* p, unsigned v) {
  asm volatile("global_store_short %0, %1, off sc0 sc1"
               :: "v"(p), "v"(v) : "memory");
}
__device__ __forceinline__ void st_flag_sys(void* p, unsigned v) {
  asm volatile("global_store_dword %0, %1, off sc0 sc1"
               :: "v"(p), "v"(v) : "memory");
}

#define WAIT_VM0()  asm volatile("s_waitcnt vmcnt(0)" ::: "memory")
#define WAIT_VM16() asm volatile("s_waitcnt vmcnt(16)" ::: "memory")
#define WAIT_LGKM() asm volatile("s_waitcnt lgkmcnt(0)" ::: "memory")
#define RAW_BAR()  do { __builtin_amdgcn_sched_barrier(0); \
                        __builtin_amdgcn_s_barrier(); \
                        __builtin_amdgcn_sched_barrier(0); } while (0)

// ---------------------------------------------------------------------------
// K0: zero sync flags each launch (graph-replay safe).
// ---------------------------------------------------------------------------
__global__ __launch_bounds__(1024) void k_reset(unsigned* __restrict__ flags) {
  flags[threadIdx.x] = 0;
}

// ---------------------------------------------------------------------------
// K1: proj_table[v][g] = emb[v]@W_ih[g] + b_ih[g] + b_hh[g]  (bf16).
// ---------------------------------------------------------------------------
__global__ __launch_bounds__(256) void k_proj(
    const float* __restrict__ emb, const float* __restrict__ W_ih,
    const float* __restrict__ b_ih, const float* __restrict__ b_hh,
    ushort* __restrict__ proj) {
  const int lane = threadIdx.x & 63;
  const int wv = threadIdx.x >> 6;
  const int vbase = (blockIdx.x * 4 + wv) * 64;
  const int lm = lane & 15, lq = lane >> 4;

  bf16x8 A[4][4];
  #pragma unroll
  for (int mt = 0; mt < 4; ++mt) {
    int v = vbase + mt * 16 + lm;
    int vc = v < VOCAB ? v : 0;
    const float* rp = emb + (size_t)vc * EMB;
    #pragma unroll
    for (int kt = 0; kt < 4; ++kt) {
      const float* p = rp + kt * 32 + lq * 8;
      #pragma unroll
      for (int i = 0; i < 8; ++i) A[mt][kt][i] = (short)f2bf(p[i]);
    }
  }
  for (int nt = 0; nt < 64; ++nt) {
    const int g = nt * 16 + lm;
    bf16x8 B[4];
    #pragma unroll
    for (int kt = 0; kt < 4; ++kt) {
      const float* p = W_ih + (size_t)g * EMB + kt * 32 + lq * 8;
      #pragma unroll
      for (int i = 0; i < 8; ++i) B[kt][i] = (short)f2bf(p[i]);
    }
    const float bias = b_ih[g] + b_hh[g];
    #pragma unroll
    for (int mt = 0; mt < 4; ++mt) {
      f32x4 acc = {0.f, 0.f, 0.f, 0.f};
      #pragma unroll
      for (int kt = 0; kt < 4; ++kt)
        acc = __builtin_amdgcn_mfma_f32_16x16x32_bf16(A[mt][kt], B[kt], acc, 0, 0, 0);
      #pragma unroll
      for (int r = 0; r < 4; ++r) {
        int row = vbase + mt * 16 + lq * 4 + r;
        if (row < VOCAB) proj[(size_t)row * G4 + g] = f2bf(acc[r] + bias);
      }
    }
  }
}

// ---------------------------------------------------------------------------
// K2: pre-swizzle W_hh into per-(parity,wave) MFMA B-fragment order; K-chunk
// slots 0..3 = block-local j-range, 4..7 = remote.
// ---------------------------------------------------------------------------
__global__ __launch_bounds__(256) void k_w2(const float* __restrict__ Whh,
                                            ushort* __restrict__ W2) {
  const int f = blockIdx.x * 256 + threadIdx.x;      // 0..32767
  const int l = f & 63, kc = (f >> 6) & 7, nt = (f >> 9) & 3;
  const int wv = (f >> 11) & 7, p = (f >> 14) & 1;
  const int ktg = (kc < 4) ? (4 * p + kc) : (4 * (1 - p) + (kc - 4));
  const int g = nt * 256 + p * 128 + wv * 16 + (l & 15);
  const int k0 = ktg * 32 + (l >> 4) * 8;
  const float* src = Whh + (size_t)g * HID + k0;
  bf16x8 o;
  #pragma unroll
  for (int i = 0; i < 8; ++i) o[i] = (short)f2bf(src[i]);
  *(bf16x8*)(W2 + (size_t)f * 8) = o;
}

// ---------------------------------------------------------------------------
// K3: persistent pair-split LSTM. sc0sc1 (MALL) handshake only — proven.
// Weights pinned into AGPRs; one barrier per step; remote RTT overlapped
// with local MFMAs; gathers issued early so no young loads at the poll.
// ---------------------------------------------------------------------------
__global__ __launch_bounds__(512, 2) void k_lstm(
    const int* __restrict__ x, const ushort* __restrict__ proj,
    const ushort* __restrict__ W2, const float* __restrict__ W_fc,
    const float* __restrict__ b_fc, float* __restrict__ out,
    ushort* __restrict__ hx, float* __restrict__ fcpart,
    unsigned* __restrict__ flags) {
  __shared__ __align__(16) ushort hbuf[2][16 * 128];  // local j-half, swizzled
  __shared__ __align__(16) int xlds[SEQ * 16];        // x transposed [t][bl]
  __shared__ float red[8][16];

  const int tid = threadIdx.x;
  const int lane = tid & 63, wv = tid >> 6;           // 8 waves
  const int lm = lane & 15, lq = lane >> 4;
  const int g16 = blockIdx.x & 15;                    // batch group
  const int p = blockIdx.x >> 4;                      // j-parity
  const int b0 = g16 * 16;
  const int pair_bid = (1 - p) * 16 + g16;

  // --- weight residency: 32 frags = 128 regs/lane, pinned in AGPRs ---
  f32x4 Wf[4][8];
  {
    const f32x4* wb = (const f32x4*)W2;
    const int base = (p * 8 + wv) * 32;
    #pragma unroll
    for (int nt = 0; nt < 4; ++nt)
      #pragma unroll
      for (int kc = 0; kc < 8; ++kc)
        Wf[nt][kc] = wb[(size_t)(base + nt * 8 + kc) * 64 + lane];
    #pragma unroll
    for (int nt = 0; nt < 4; ++nt)
      #pragma unroll
      for (int kc = 0; kc < 8; ++kc)
        asm volatile("" : "+a"(Wf[nt][kc]));          // pin in AGPR file
  }
  #define WFRAG(nt, kc) __builtin_bit_cast(bf16x8, Wf[nt][kc])

  // x preload transposed: xlds[t*16+bl]
  for (int i = tid; i < SEQ * 16; i += 512) {
    int bl = i >> 9, t = i & 511;
    xlds[t * 16 + bl] = x[(b0 + bl) * SEQ + t];
  }
  for (int i = tid; i < 16 * 128; i += 512) hbuf[0][i] = 0;

  unsigned* my_flag = flags + blockIdx.x * 16;
  const unsigned* rm_flag = flags + pair_bid * 16;
  ushort* my_h = hx + (size_t)((p * 16 + g16) * 2) * 2048;
  const ushort* rm_h = hx + (size_t)(((1 - p) * 16 + g16) * 2) * 2048;

  float c[4] = {0.f, 0.f, 0.f, 0.f};
  float hlast[4] = {0.f, 0.f, 0.f, 0.f};

  int gcol[4];
  #pragma unroll
  for (int nt = 0; nt < 4; ++nt) gcol[nt] = nt * 256 + p * 128 + wv * 16 + lm;

  __syncthreads();

  // t=0 x_proj gather
  ushort xpv[4][4];
  {
    i32x4 i0 = *(const i32x4*)&xlds[lq * 4];
    #pragma unroll
    for (int r = 0; r < 4; ++r) {
      const ushort* rp = proj + (size_t)i0[r] * G4;
      #pragma unroll
      for (int nt = 0; nt < 4; ++nt) xpv[nt][r] = rp[gcol[nt]];
    }
  }

  unsigned pf = 0;   // prefetched partner flag (validated by step-end vmcnt0)
  int cur = 0;
  #pragma clang loop unroll(disable)
  for (int t = 0; t < SEQ; ++t) {
    const int nxt = cur ^ 1;

    // acc init from current xp (gathers from last step: long retired)
    f32x4 acc[4];
    #pragma unroll
    for (int nt = 0; nt < 4; ++nt)
      #pragma unroll
      for (int r = 0; r < 4; ++r) acc[nt][r] = bf2f(xpv[nt][r]);

    if (t > 0) {
      // local A-frags first (LDS latency hides under the poll)
      bf16x8 Al[4];
      {
        const char* hb = (const char*)hbuf[cur];
        #pragma unroll
        for (int c4 = 0; c4 < 4; ++c4) {
          int byte = (lm * 256 + c4 * 64 + lq * 16) ^ ((lm & 7) << 4);
          Al[c4] = *(const bf16x8*)(hb + byte);
        }
      }
      // poll partner flag; pf often already satisfies it
      {
        unsigned f = pf;
        while (f < (unsigned)t) f = ld_flag_sys(rm_flag);
      }
      // remote h loads (oldest in vmem queue) ...
      bf16x8 Ar[4];
      {
        const char* rb = (const char*)(rm_h + cur * 2048);
        ldx4_sys(Ar[0], rb + (lm * 256 + 0 * 64 + lq * 16));
        ldx4_sys(Ar[1], rb + (lm * 256 + 1 * 64 + lq * 16));
        ldx4_sys(Ar[2], rb + (lm * 256 + 2 * 64 + lq * 16));
        ldx4_sys(Ar[3], rb + (lm * 256 + 3 * 64 + lq * 16));
      }
      // ... then next-step gathers (ancient by the next poll)
      {
        i32x4 idx4 = *(const i32x4*)&xlds[((t + 1 < SEQ) ? t + 1 : t) * 16 + lq * 4];
        #pragma unroll
        for (int r = 0; r < 4; ++r) {
          const ushort* rp = proj + (size_t)idx4[r] * G4;
          #pragma unroll
          for (int nt = 0; nt < 4; ++nt) xpv[nt][r] = rp[gcol[nt]];
        }
      }
      // local MFMAs hide the remote RTT
      #pragma unroll
      for (int c4 = 0; c4 < 4; ++c4)
        #pragma unroll
        for (int nt = 0; nt < 4; ++nt)
          acc[nt] = __builtin_amdgcn_mfma_f32_16x16x32_bf16(Al[c4], WFRAG(nt, c4), acc[nt], 0, 0, 0);
      WAIT_VM16();                        // 4 remote loads retired; gathers fly
      __builtin_amdgcn_sched_barrier(0);  // rule #18
      #pragma unroll
      for (int c4 = 0; c4 < 4; ++c4)
        #pragma unroll
        for (int nt = 0; nt < 4; ++nt)
          acc[nt] = __builtin_amdgcn_mfma_f32_16x16x32_bf16(Ar[c4], WFRAG(nt, 4 + c4), acc[nt], 0, 0, 0);
    } else {
      // t==0: h=0, gates = xp only; just issue the t=1 gathers
      i32x4 idx4 = *(const i32x4*)&xlds[16 + lq * 4];
      #pragma unroll
      for (int r = 0; r < 4; ++r) {
        const ushort* rp = proj + (size_t)idx4[r] * G4;
        #pragma unroll
        for (int nt = 0; nt < 4; ++nt) xpv[nt][r] = rp[gcol[nt]];
      }
    }

    // activations: lane owns (b = lq*4+r, j = p*128 + wv*16 + lm)
    ushort hh[4];
    #pragma unroll
    for (int r = 0; r < 4; ++r) {
      float si = sigm(acc[0][r]);
      float sf = sigm(acc[1][r]);
      float tg = tanh_fast(acc[2][r]);
      float so = sigm(acc[3][r]);
      float cn = sf * c[r] + si * tg;
      c[r] = cn;
      float h = so * tanh_fast(cn);
      hlast[r] = h;
      hh[r] = f2bf(h);
      const int bl = lq * 4 + r;
      int byte = (bl * 256 + (wv * 16 + lm) * 2) ^ ((bl & 7) << 4);
      *(ushort*)((char*)hbuf[nxt] + byte) = hh[r];
    }

    // publish own half directly from registers + prefetch partner flag
    if (t + 1 < SEQ) {
      ushort* mb = my_h + (size_t)nxt * 2048;
      #pragma unroll
      for (int r = 0; r < 4; ++r)
        st16_sys(mb + (lq * 4 + r) * 128 + wv * 16 + lm, (unsigned)hh[r]);
      pf = ld_flag_issue(rm_flag);   // validated by the vmcnt(0) below
    }
    WAIT_VM0();      // publish acked at MALL (+ pf valid; gathers were old)
    WAIT_LGKM();     // hbuf[nxt] visible
    RAW_BAR();       // single barrier per step
    if (t + 1 < SEQ && tid == 0) st_flag_sys(my_flag, (unsigned)(t + 1));
    cur = nxt;
  }

  // --- FC + sigmoid epilogue (pair-split partials, compiler atomics) ---
  float pl[4];
  const float wfc = W_fc[p * 128 + wv * 16 + lm];
  #pragma unroll
  for (int r = 0; r < 4; ++r) pl[r] = hlast[r] * wfc;
  #pragma unroll
  for (int d = 1; d < 16; d <<= 1) {
    #pragma unroll
    for (int r = 0; r < 4; ++r) pl[r] += __shfl_xor(pl[r], d);
  }
  if (lm == 0) {
    #pragma unroll
    for (int r = 0; r < 4; ++r) red[wv][lq * 4 + r] = pl[r];
  }
  __syncthreads();
  if (tid < 16) {
    float s = 0.f;
    #pragma unroll
    for (int w = 0; w < 8; ++w) s += red[w][tid];
    if (p == 1) {
      fcpart[g16 * 16 + tid] = s;
      asm volatile("s_waitcnt vmcnt(0)" ::: "memory");
      __hip_atomic_store(my_flag, (unsigned)(SEQ + 1), __ATOMIC_RELEASE,
                         __HIP_MEMORY_SCOPE_AGENT);
    } else {
      while (__hip_atomic_load(rm_flag, __ATOMIC_ACQUIRE, __HIP_MEMORY_SCOPE_AGENT) <
             (unsigned)(SEQ + 1))
        __builtin_amdgcn_s_sleep(1);
      float v = fcpart[g16 * 16 + tid];
      out[b0 + tid] = sigm(s + v + b_fc[0]);
    }
  }
}

// ---------------------------------------------------------------------------
extern "C" void kernel_launch(void* const* d_in, const int* in_sizes, int n_in,
                              void* d_out, int out_size, void* d_ws, size_t ws_size,
                              hipStream_t stream) {
  const int*   x    = (const int*)d_in[0];
  const float* emb  = (const float*)d_in[1];
  const float* W_ih = (const float*)d_in[2];
  const float* W_hh = (const float*)d_in[3];
  const float* b_ih = (const float*)d_in[4];
  const float* b_hh = (const float*)d_in[5];
  const float* W_fc = (const float*)d_in[6];
  const float* b_fc = (const float*)d_in[7];
  float* out = (float*)d_out;

  // ws: proj 102,400,000 | W2 524,288 | hx 262,144 | fcpart 1,024 | flags 4,096
  char* ws = (char*)d_ws;
  ushort*   proj   = (ushort*)ws;
  ushort*   W2     = (ushort*)(ws + 102400000);
  ushort*   hx     = (ushort*)(ws + 102924288);
  float*    fcpart = (float*)(ws + 103186432);
  unsigned* flags  = (unsigned*)(ws + 103187456);

  k_reset<<<dim3(1), dim3(1024), 0, stream>>>(flags);
  k_proj<<<dim3(196), dim3(256), 0, stream>>>(emb, W_ih, b_ih, b_hh, proj);
  k_w2<<<dim3(128), dim3(256), 0, stream>>>(W_hh, W2);
  k_lstm<<<dim3(32), dim3(512), 0, stream>>>(x, proj, W2, W_fc, b_fc, out,
                                             hx, fcpart, flags);
}